// Round 10
// baseline (8782.915 us; speedup 1.0000x reference)
//
#include <hip/hip_runtime.h>
#include <math.h>

#define NSCORE 200000
#define THRF   0.30f
#define ROWCAP 4096
#define BCAP2  64
#define NBIN   1024
#define HLO3   0.30f
#define HSC3   2275.5556f   // NBIN / 0.45
#define COLCAP 128

typedef unsigned short u16;
typedef __attribute__((ext_vector_type(8))) short short8;
typedef __attribute__((ext_vector_type(4))) float f32x4;
typedef __attribute__((ext_vector_type(4))) unsigned int uint4v;

__device__ __forceinline__ bool better(float av, int ai, float bv, int bi) {
    return (av > bv) || (av == bv && ai < bi);
}

__device__ __forceinline__ void split8(float4 a, float4 b, short8& hi, short8& lo) {
    float f[8] = {a.x, a.y, a.z, a.w, b.x, b.y, b.z, b.w};
    uint4v H, L;
    #pragma unroll
    for (int i = 0; i < 4; ++i) {
        unsigned ue = __float_as_uint(f[2 * i]);
        unsigned uo = __float_as_uint(f[2 * i + 1]);
        unsigned he = ue & 0xFFFF0000u;
        unsigned ho = uo & 0xFFFF0000u;
        float le  = f[2 * i]     - __uint_as_float(he);
        float lo_ = f[2 * i + 1] - __uint_as_float(ho);
        H[i] = (he >> 16) | ho;
        L[i] = (__float_as_uint(le) >> 16) | (__float_as_uint(lo_) & 0xFFFF0000u);
    }
    hi = __builtin_bit_cast(short8, H);
    lo = __builtin_bit_cast(short8, L);
}

// ---------------- K1: encoder (weights via uniform GLOBAL reads -> s_load) ----------------
template<int REP>
__global__ __launch_bounds__(128) void k_encoder_t(
    const float* __restrict__ x,
    const float* __restrict__ w1, const float* __restrict__ b1,
    const float* __restrict__ w2, const float* __restrict__ b2,
    const float* __restrict__ w3, const float* __restrict__ b3,
    const float* __restrict__ w4, const float* __restrict__ b4,
    const float* __restrict__ wf, float* __restrict__ bxR,
    u16* __restrict__ bxh, u16* __restrict__ bxl,
    unsigned int* __restrict__ cnt) {
    __shared__ float xs[8][128];      // stride-1 over l -> conflict-free
    __shared__ float sacc[128 * 65];  // padded
    __shared__ float part[2][64];
    __shared__ float vecs[64];
    const int b = blockIdx.x, tid = threadIdx.x;

    if (tid == 0) cnt[b] = 0;
    {
        const float4* xr = (const float4*)(x + (size_t)b * 1024);
        float4 p0 = xr[tid * 2], p1 = xr[tid * 2 + 1];
        xs[0][tid] = p0.x; xs[1][tid] = p0.y; xs[2][tid] = p0.z; xs[3][tid] = p0.w;
        xs[4][tid] = p1.x; xs[5][tid] = p1.y; xs[6][tid] = p1.z; xs[7][tid] = p1.w;
    }
    __syncthreads();

    const int l = tid;
    #pragma unroll 1
    for (int rep = 0; rep < REP; ++rep) {
        #pragma unroll 1
        for (int o = 0; o < 64; ++o) {
            int br = o >> 4, oo = o & 15;
            float val;
            if (br == 0) {
                val = b1[oo];
                #pragma unroll
                for (int c = 0; c < 8; ++c) val = fmaf(w1[oo * 8 + c], xs[c][l], val);
            } else {
                const float* W  = (br == 1) ? w2 : (br == 2) ? w3 : w4;
                const float* Bb = (br == 1) ? b2 : (br == 2) ? b3 : b4;
                int dil = 1 << (br - 1);
                val = Bb[oo];
                #pragma unroll
                for (int t = 0; t < 3; ++t) {
                    int ll = l + dil * (t - 1);
                    if (ll >= 0 && ll < 128) {
                        #pragma unroll
                        for (int c = 0; c < 8; ++c)
                            val = fmaf(W[oo * 24 + c * 3 + t], xs[c][ll], val);
                    }
                }
            }
            val = 0.5f * val * (1.0f + erff(val * 0.70710678118654752f));  // exact GELU
            sacc[l * 65 + o] = val;
        }
        __syncthreads();
        {
            int o = tid & 63, h = tid >> 6;
            float vs = 0.f;
            #pragma unroll
            for (int j = 0; j < 64; ++j) vs += sacc[(h * 64 + j) * 65 + o];
            part[h][o] = vs;
        }
        __syncthreads();
        if (tid < 64) vecs[tid] = (part[0][tid] + part[1][tid]) * (1.0f / 128.0f);
        __syncthreads();
        if (tid < 64) {
            const float* wr = wf + tid * 64;
            float o = 0.f;
            #pragma unroll
            for (int j = 0; j < 64; ++j) o = fmaf(vecs[j], wr[j], o);
            float mu = o;
            #pragma unroll
            for (int off = 32; off > 0; off >>= 1) mu += __shfl_xor(mu, off);
            mu *= (1.0f / 64.0f);
            float d = o - mu;
            float s2 = d * d;
            #pragma unroll
            for (int off = 32; off > 0; off >>= 1) s2 += __shfl_xor(s2, off);
            float ln = d / sqrtf(s2 * (1.0f / 64.0f) + 1e-5f);
            float n2 = ln * ln;
            #pragma unroll
            for (int off = 32; off > 0; off >>= 1) n2 += __shfl_xor(n2, off);
            float nrm = sqrtf(n2);
            float v = ln / fmaxf(nrm, 1e-12f);
            bxR[b * 64 + tid] = v;
            unsigned u = __float_as_uint(v);
            unsigned h = u & 0xFFFF0000u;
            float lo = v - __uint_as_float(h);
            bxh[b * 64 + tid] = (u16)(u >> 16);
            bxl[b * 64 + tid] = (u16)(__float_as_uint(lo) >> 16);
        }
        __syncthreads();
    }
}

// ------- K2: MFMA scores, 1024 rows/block (16 segs), depth-1 prefetch, single flush -------
template<int REP>
__global__ __launch_bounds__(256) void k_scores_t(const float* __restrict__ ax,
                                                  const u16* __restrict__ bxh,
                                                  const u16* __restrict__ bxl,
                                                  unsigned int* __restrict__ cnt,
                                                  float* __restrict__ candv,
                                                  int* __restrict__ candi) {
    __shared__ uint4v shv[576];           // bxh staged, row stride 72 u16
    __shared__ uint4v slv[576];
    __shared__ float sval[64][BCAP2];     // 16 KB
    __shared__ int   sidx[64][BCAP2];     // 16 KB
    __shared__ unsigned int scnt[64];
    __shared__ unsigned int sbase[64];
    const int tid = threadIdx.x;

    {
        const uint4v* srch = (const uint4v*)bxh;
        const uint4v* srcl = (const uint4v*)bxl;
        for (int i = tid; i < 512; i += 256) {
            int r = i >> 3, j = i & 7;
            shv[r * 9 + j] = srch[i];
            slv[r * 9 + j] = srcl[i];
        }
    }
    __syncthreads();

    const int lane = tid & 63;
    const int w = tid >> 6;
    const int lm = lane & 15;   // A-row / B-col / D-col within tile
    const int lg = lane >> 4;   // k-group

    short8 Bh[4][2], Bl[4][2];
    const u16* sh = (const u16*)shv;
    const u16* sl = (const u16*)slv;
    #pragma unroll
    for (int t = 0; t < 4; ++t) {
        #pragma unroll
        for (int c = 0; c < 2; ++c) {
            int off = (16 * t + lm) * 72 + c * 32 + lg * 8;
            Bh[t][c] = *(const short8*)(sh + off);
            Bl[t][c] = *(const short8*)(sl + off);
        }
    }

    #pragma unroll 1
    for (int rep = 0; rep < REP; ++rep) {
        if (tid < 64) scnt[tid] = 0;
        __syncthreads();

        const float4* rp0;
        {
            int nr = blockIdx.x * 1024 + w * 16 + lm;
            int nrc = nr < NSCORE ? nr : NSCORE - 1;
            rp0 = (const float4*)(ax + (size_t)nrc * 64);
        }
        float4 q0 = rp0[lg * 2], q1 = rp0[lg * 2 + 1];
        float4 q2 = rp0[8 + lg * 2], q3 = rp0[9 + lg * 2];

        #pragma unroll 1
        for (int s = 0; s < 16; ++s) {
            float4 p0, p1, p2, p3;
            if (s < 15) {
                int nr = blockIdx.x * 1024 + (s + 1) * 64 + w * 16 + lm;
                int nrc = nr < NSCORE ? nr : NSCORE - 1;
                const float4* np = (const float4*)(ax + (size_t)nrc * 64);
                p0 = np[lg * 2];     p1 = np[lg * 2 + 1];
                p2 = np[8 + lg * 2]; p3 = np[9 + lg * 2];
            }

            short8 Ah[2], Al[2];
            split8(q0, q1, Ah[0], Al[0]);
            split8(q2, q3, Ah[1], Al[1]);

            f32x4 acc[4];
            #pragma unroll
            for (int t = 0; t < 4; ++t) acc[t] = (f32x4){0.f, 0.f, 0.f, 0.f};

            #pragma unroll
            for (int t = 0; t < 4; ++t) {
                #pragma unroll
                for (int c = 0; c < 2; ++c) {
                    acc[t] = __builtin_amdgcn_mfma_f32_16x16x32_bf16(Ah[c], Bh[t][c], acc[t], 0, 0, 0);
                    acc[t] = __builtin_amdgcn_mfma_f32_16x16x32_bf16(Ah[c], Bl[t][c], acc[t], 0, 0, 0);
                    acc[t] = __builtin_amdgcn_mfma_f32_16x16x32_bf16(Al[c], Bh[t][c], acc[t], 0, 0, 0);
                }
            }

            const int n0 = blockIdx.x * 1024 + s * 64 + w * 16;
            #pragma unroll
            for (int t = 0; t < 4; ++t) {
                #pragma unroll
                for (int r = 0; r < 4; ++r) {
                    float v = acc[t][r];
                    int n = n0 + lg * 4 + r;     // D-row = n
                    if (v > THRF && n < NSCORE) {
                        int row = t * 16 + lm;   // D-col = b
                        unsigned int p = atomicAdd(&scnt[row], 1u);
                        if (p < BCAP2) { sval[row][p] = v; sidx[row][p] = n; }
                    }
                }
            }
            q0 = p0; q1 = p1; q2 = p2; q3 = p3;
        }
        __syncthreads();

        if (tid < 64) {
            unsigned int c = min(scnt[tid], (unsigned int)BCAP2);
            sbase[tid] = c ? atomicAdd(&cnt[tid], c) : 0u;
        }
        __syncthreads();

        for (int s = tid; s < 64 * BCAP2; s += 256) {
            int bb = s >> 6, j = s & (BCAP2 - 1);
            if (j < (int)min(scnt[bb], (unsigned int)BCAP2)) {
                unsigned int pos = sbase[bb] + (unsigned int)j;
                if (pos < ROWCAP) {
                    candv[(size_t)bb * ROWCAP + pos] = sval[bb][j];
                    candi[(size_t)bb * ROWCAP + pos] = sidx[bb][j];
                }
            }
        }
        __syncthreads();
    }
}

// ------- K3: hist cutoff -> exact f32 recompute -> exact top-16 -------
__global__ __launch_bounds__(256) void k_select(const unsigned int* __restrict__ cnt,
                                                const float* __restrict__ candv,
                                                const int* __restrict__ candi,
                                                const float* __restrict__ ax,
                                                const float* __restrict__ bxR,
                                                float* __restrict__ out,
                                                int* __restrict__ tkidx) {
    __shared__ unsigned int hist[NBIN];
    __shared__ float colv[COLCAP];
    __shared__ int   coli[COLCAP];
    __shared__ int   colc;
    __shared__ int   Bsh;
    const int b = blockIdx.x;
    const int t = threadIdx.x;

    for (int i = t; i < NBIN; i += 256) hist[i] = 0;
    if (t == 0) { colc = 0; Bsh = 0; }
    __syncthreads();

    const int cs = (int)min(cnt[b], (unsigned int)ROWCAP);
    for (int i = t; i < cs; i += 256) {
        float v = candv[(size_t)b * ROWCAP + i];
        int bin = (int)((v - HLO3) * HSC3);
        bin = bin < 0 ? 0 : (bin > NBIN - 1 ? NBIN - 1 : bin);
        atomicAdd(&hist[bin], 1u);
    }
    __syncthreads();

    if (t < 64) {
        const int base = 1023 - t * 16;
        unsigned int loc[16]; unsigned int sg = 0;
        #pragma unroll
        for (int j = 0; j < 16; ++j) { loc[j] = hist[base - j]; sg += loc[j]; }
        unsigned int cum = sg;
        #pragma unroll
        for (int off = 1; off < 64; off <<= 1) {
            unsigned int u = __shfl_up(cum, off);
            if (t >= off) cum += u;
        }
        unsigned int prev = cum - sg;
        if ((prev < 16u) && (cum >= 16u)) {
            unsigned int run = prev; int Bv = 0;
            #pragma unroll
            for (int j = 0; j < 16; ++j) {
                run += loc[j];
                if (run >= 16u) { Bv = base - j; break; }
            }
            Bsh = Bv;
        }
    }
    __syncthreads();
    const int B2 = Bsh >= 2 ? Bsh - 2 : 0;

    for (int i = t; i < cs; i += 256) {
        float v = candv[(size_t)b * ROWCAP + i];
        int bin = (int)((v - HLO3) * HSC3);
        bin = bin < 0 ? 0 : (bin > NBIN - 1 ? NBIN - 1 : bin);
        if (bin >= B2) {
            int p = atomicAdd(&colc, 1);
            if (p < COLCAP) { colv[p] = v; coli[p] = candi[(size_t)b * ROWCAP + i]; }
        }
    }
    __syncthreads();

    {   // exact f32 recompute of finalists
        int m = colc; if (m > COLCAP) m = COLCAP;
        if (t < m) {
            int idx = coli[t];
            idx = idx < 0 ? 0 : (idx > NSCORE - 1 ? NSCORE - 1 : idx);
            const float4* arw = (const float4*)(ax + (size_t)idx * 64);
            const float4* brw = (const float4*)(bxR + b * 64);
            float s = 0.f;
            #pragma unroll
            for (int i = 0; i < 16; ++i) {
                float4 av = arw[i], bv = brw[i];
                s = fmaf(av.x, bv.x, s);
                s = fmaf(av.y, bv.y, s);
                s = fmaf(av.z, bv.z, s);
                s = fmaf(av.w, bv.w, s);
            }
            colv[t] = s;
        }
    }
    __syncthreads();

    if (t < 64) {
        int m = colc; if (m > COLCAP) m = COLCAP;
        float v0 = (t      < m) ? colv[t]      : -INFINITY;
        float v1 = (t + 64 < m) ? colv[t + 64] : -INFINITY;
        int i0 = (t      < m) ? coli[t]      : 0x7FFFFFFF;
        int i1 = (t + 64 < m) ? coli[t + 64] : 0x7FFFFFFF;
        for (int r = 0; r < 16; ++r) {
            float bv; int bi; int bs;
            if (better(v0, i0, v1, i1)) { bv = v0; bi = i0; bs = 0; }
            else                        { bv = v1; bi = i1; bs = 1; }
            int bl = t;
            #pragma unroll
            for (int off = 32; off > 0; off >>= 1) {
                float ov = __shfl_xor(bv, off);
                int oi = __shfl_xor(bi, off);
                int ol = __shfl_xor(bl, off);
                int os = __shfl_xor(bs, off);
                if (better(ov, oi, bv, bi)) { bv = ov; bi = oi; bl = ol; bs = os; }
            }
            if (t == 0) { out[b * 16 + r] = bv; tkidx[b * 16 + r] = bi; }
            if (t == bl) {
                if (bs == 0) { v0 = -INFINITY; i0 = 0x7FFFFFFF; }
                else         { v1 = -INFINITY; i1 = 0x7FFFFFFF; }
            }
        }
    }
}

// ---------------- K4: gather windows + transpose (1024 parallel blocks) ----------------
__global__ __launch_bounds__(128) void k_gather(const float* __restrict__ win,
                                                const int* __restrict__ tkidx,
                                                float* __restrict__ out) {
    __shared__ float sm[9 * 128];
    const int bk = blockIdx.x;
    const int l = threadIdx.x;
    int idx = tkidx[bk];
    idx = idx < 0 ? 0 : (idx > NSCORE - 1 ? NSCORE - 1 : idx);
    const float* src = win + (size_t)idx * 1152;
    #pragma unroll
    for (int c = 0; c < 9; ++c) sm[c * 128 + l] = src[c * 128 + l];
    __syncthreads();
    float* dst = out + 1024 + (size_t)bk * 1152;
    #pragma unroll
    for (int q = 0; q < 9; ++q) {
        int j = q * 128 + l;
        dst[j] = sm[(j % 9) * 128 + (j / 9)];
    }
}

extern "C" void kernel_launch(void* const* d_in, const int* in_sizes, int n_in,
                              void* d_out, int out_size, void* d_ws, size_t ws_size,
                              hipStream_t stream) {
    const float* x   = (const float*)d_in[0];
    const float* ax  = (const float*)d_in[1];
    const float* win = (const float*)d_in[2];
    const float* w1  = (const float*)d_in[3];
    const float* b1  = (const float*)d_in[4];
    const float* w2  = (const float*)d_in[5];
    const float* b2  = (const float*)d_in[6];
    const float* w3  = (const float*)d_in[7];
    const float* b3  = (const float*)d_in[8];
    const float* w4  = (const float*)d_in[9];
    const float* b4  = (const float*)d_in[10];
    const float* wf  = (const float*)d_in[11];
    float* out = (float*)d_out;

    float* wsf = (float*)d_ws;
    float* bxR = wsf;                                   // 4096 f32
    u16*   bxh = (u16*)(wsf + 4096);                    // 4096 u16
    u16*   bxl = bxh + 4096;                            // 4096 u16
    unsigned int* cntp = (unsigned int*)(bxl + 4096);   // 64 u32
    float* candv = (float*)(cntp + 64);                 // 64*4096 f32
    int*   candi = (int*)(candv + (size_t)64 * ROWCAP); // 64*4096 i32
    int*   tkidx = candi + (size_t)64 * ROWCAP;         // 1024 i32
    // dummies for probes
    float* bxRd = (float*)(tkidx + 1024);
    u16*   bxhd = (u16*)(bxRd + 4096);
    u16*   bxld = bxhd + 4096;
    unsigned int* cntd = (unsigned int*)(bxld + 4096);
    float* candvd = (float*)(cntd + 64);
    int*   candid = (int*)(candvd + (size_t)64 * ROWCAP);

    // ---- real pipeline (4 nodes) ----
    hipLaunchKernelGGL(HIP_KERNEL_NAME(k_encoder_t<1>), dim3(64), dim3(128), 0, stream,
                       x, w1, b1, w2, b2, w3, b3, w4, b4, wf, bxR, bxh, bxl, cntp);
    hipLaunchKernelGGL(HIP_KERNEL_NAME(k_scores_t<1>), dim3(196), dim3(256), 0, stream,
                       ax, bxh, bxl, cntp, candv, candi);
    hipLaunchKernelGGL(k_select, dim3(64), dim3(256), 0, stream,
                       cntp, candv, candi, ax, bxR, out, tkidx);
    hipLaunchKernelGGL(k_gather, dim3(64 * 16), dim3(128), 0, stream,
                       win, tkidx, out);

    // ---- diagnostic probes (write only dummy buffers; land in rocprof top-5) ----
    hipLaunchKernelGGL(HIP_KERNEL_NAME(k_encoder_t<256>), dim3(64), dim3(128), 0, stream,
                       x, w1, b1, w2, b2, w3, b3, w4, b4, wf, bxRd, bxhd, bxld, cntd);
    hipLaunchKernelGGL(HIP_KERNEL_NAME(k_scores_t<96>), dim3(196), dim3(256), 0, stream,
                       ax, bxhd, bxld, cntd, candvd, candid);
}

// Round 11
// 62.899 us; speedup vs baseline: 139.6358x; 139.6358x over previous
//
#include <hip/hip_runtime.h>
#include <math.h>

#define NSCORE 200000
#define THRF   0.30f
#define ROWCAP 4096
#define BCAP2  64
#define NBIN   1024
#define HLO3   0.30f
#define HSC3   2275.5556f   // NBIN / 0.45
#define COLCAP 128

typedef unsigned short u16;
typedef __attribute__((ext_vector_type(8))) short short8;
typedef __attribute__((ext_vector_type(4))) float f32x4;
typedef __attribute__((ext_vector_type(4))) unsigned int uint4v;

__device__ __forceinline__ bool better(float av, int ai, float bv, int bi) {
    return (av > bv) || (av == bv && ai < bi);
}

__device__ __forceinline__ const float* uniform_ptr(const float* p) {
    unsigned long long u = (unsigned long long)p;
    unsigned lo = __builtin_amdgcn_readfirstlane((unsigned)u);
    unsigned hi = __builtin_amdgcn_readfirstlane((unsigned)(u >> 32));
    return (const float*)(((unsigned long long)hi << 32) | (unsigned long long)lo);
}

__device__ __forceinline__ void split8(float4 a, float4 b, short8& hi, short8& lo) {
    float f[8] = {a.x, a.y, a.z, a.w, b.x, b.y, b.z, b.w};
    uint4v H, L;
    #pragma unroll
    for (int i = 0; i < 4; ++i) {
        unsigned ue = __float_as_uint(f[2 * i]);
        unsigned uo = __float_as_uint(f[2 * i + 1]);
        unsigned he = ue & 0xFFFF0000u;
        unsigned ho = uo & 0xFFFF0000u;
        float le  = f[2 * i]     - __uint_as_float(he);
        float lo_ = f[2 * i + 1] - __uint_as_float(ho);
        H[i] = (he >> 16) | ho;
        L[i] = (__float_as_uint(le) >> 16) | (__float_as_uint(lo_) & 0xFFFF0000u);
    }
    hi = __builtin_bit_cast(short8, H);
    lo = __builtin_bit_cast(short8, L);
}

// ---- K1: encoder, 512 threads: wave-group g owns conv branch g (16 outputs each) ----
__global__ __launch_bounds__(512) void k_encoder(
    const float* __restrict__ x,
    const float* __restrict__ w1, const float* __restrict__ b1,
    const float* __restrict__ w2, const float* __restrict__ b2,
    const float* __restrict__ w3, const float* __restrict__ b3,
    const float* __restrict__ w4, const float* __restrict__ b4,
    const float* __restrict__ wf, float* __restrict__ bxR,
    u16* __restrict__ bxh, u16* __restrict__ bxl,
    unsigned int* __restrict__ cnt) {
    __shared__ float xsp[128][12];    // padded: rows 48B (16B-aligned), 2-way alias only
    __shared__ float sacc[128 * 65];  // [l][o], stride 65 -> conflict-free
    __shared__ float part[8][64];
    __shared__ float vecs[64];
    const int b = blockIdx.x, tid = threadIdx.x;
    const int g = tid >> 7, l = tid & 127;

    if (tid == 0) cnt[b] = 0;

    float xr[8];
    {
        const float4* xrow = (const float4*)(x + (size_t)b * 1024 + l * 8);
        float4 a = xrow[0], c = xrow[1];
        xr[0] = a.x; xr[1] = a.y; xr[2] = a.z; xr[3] = a.w;
        xr[4] = c.x; xr[5] = c.y; xr[6] = c.z; xr[7] = c.w;
        if (g == 0) {
            *(float4*)&xsp[l][0] = a;
            *(float4*)&xsp[l][4] = c;
        }
    }
    __syncthreads();

    {
        const float* W;  const float* Bb;
        if      (g == 0) { W = w1; Bb = b1; }
        else if (g == 1) { W = w2; Bb = b2; }
        else if (g == 2) { W = w3; Bb = b3; }
        else             { W = w4; Bb = b4; }
        W = uniform_ptr(W); Bb = uniform_ptr(Bb);          // -> s_load via K$
        const int dil = (g == 0) ? 0 : (1 << (g - 1));

        #pragma unroll 1
        for (int i = 0; i < 16; ++i) {
            float val = Bb[i];
            if (g == 0) {
                #pragma unroll
                for (int c = 0; c < 8; ++c) val = fmaf(W[i * 8 + c], xr[c], val);
            } else {
                int ll = l - dil;                           // tap t=0 (left)
                if (ll >= 0) {
                    float4 a = *(const float4*)&xsp[ll][0];
                    float4 c4 = *(const float4*)&xsp[ll][4];
                    float xv[8] = {a.x, a.y, a.z, a.w, c4.x, c4.y, c4.z, c4.w};
                    #pragma unroll
                    for (int c = 0; c < 8; ++c) val = fmaf(W[i * 24 + c * 3 + 0], xv[c], val);
                }
                #pragma unroll                               // tap t=1 (center, registers)
                for (int c = 0; c < 8; ++c) val = fmaf(W[i * 24 + c * 3 + 1], xr[c], val);
                ll = l + dil;                                // tap t=2 (right)
                if (ll < 128) {
                    float4 a = *(const float4*)&xsp[ll][0];
                    float4 c4 = *(const float4*)&xsp[ll][4];
                    float xv[8] = {a.x, a.y, a.z, a.w, c4.x, c4.y, c4.z, c4.w};
                    #pragma unroll
                    for (int c = 0; c < 8; ++c) val = fmaf(W[i * 24 + c * 3 + 2], xv[c], val);
                }
            }
            val = 0.5f * val * (1.0f + erff(val * 0.70710678118654752f));  // exact GELU
            sacc[l * 65 + (g * 16 + i)] = val;
        }
    }
    __syncthreads();
    {
        int o = tid & 63, h = tid >> 6;
        float vs = 0.f;
        #pragma unroll
        for (int j = 0; j < 16; ++j) vs += sacc[(h * 16 + j) * 65 + o];
        part[h][o] = vs;
    }
    __syncthreads();
    if (tid < 64) {
        float v = ((part[0][tid] + part[1][tid]) + (part[2][tid] + part[3][tid]))
                + ((part[4][tid] + part[5][tid]) + (part[6][tid] + part[7][tid]));
        vecs[tid] = v * (1.0f / 128.0f);
    }
    __syncthreads();
    if (tid < 64) {
        const float* wr = wf + tid * 64;
        float o = 0.f;
        #pragma unroll
        for (int j = 0; j < 64; ++j) o = fmaf(vecs[j], wr[j], o);
        float mu = o;
        #pragma unroll
        for (int off = 32; off > 0; off >>= 1) mu += __shfl_xor(mu, off);
        mu *= (1.0f / 64.0f);
        float d = o - mu;
        float s2 = d * d;
        #pragma unroll
        for (int off = 32; off > 0; off >>= 1) s2 += __shfl_xor(s2, off);
        float ln = d / sqrtf(s2 * (1.0f / 64.0f) + 1e-5f);
        float n2 = ln * ln;
        #pragma unroll
        for (int off = 32; off > 0; off >>= 1) n2 += __shfl_xor(n2, off);
        float nrm = sqrtf(n2);
        float v = ln / fmaxf(nrm, 1e-12f);
        bxR[b * 64 + tid] = v;
        unsigned u = __float_as_uint(v);
        unsigned h = u & 0xFFFF0000u;
        float lo = v - __uint_as_float(h);
        bxh[b * 64 + tid] = (u16)(u >> 16);
        bxl[b * 64 + tid] = (u16)(__float_as_uint(lo) >> 16);
    }
}

// ------- K2: MFMA scores, 1024 rows/block (16 segs), depth-1 prefetch, single flush -------
__global__ __launch_bounds__(256) void k_scores(const float* __restrict__ ax,
                                                const u16* __restrict__ bxh,
                                                const u16* __restrict__ bxl,
                                                unsigned int* __restrict__ cnt,
                                                float* __restrict__ candv,
                                                int* __restrict__ candi) {
    __shared__ uint4v shv[576];
    __shared__ uint4v slv[576];
    __shared__ float sval[64][BCAP2];
    __shared__ int   sidx[64][BCAP2];
    __shared__ unsigned int scnt[64];
    __shared__ unsigned int sbase[64];
    const int tid = threadIdx.x;

    {
        const uint4v* srch = (const uint4v*)bxh;
        const uint4v* srcl = (const uint4v*)bxl;
        for (int i = tid; i < 512; i += 256) {
            int r = i >> 3, j = i & 7;
            shv[r * 9 + j] = srch[i];
            slv[r * 9 + j] = srcl[i];
        }
    }
    if (tid < 64) scnt[tid] = 0;
    __syncthreads();

    const int lane = tid & 63;
    const int w = tid >> 6;
    const int lm = lane & 15;
    const int lg = lane >> 4;

    short8 Bh[4][2], Bl[4][2];
    const u16* sh = (const u16*)shv;
    const u16* sl = (const u16*)slv;
    #pragma unroll
    for (int t = 0; t < 4; ++t) {
        #pragma unroll
        for (int c = 0; c < 2; ++c) {
            int off = (16 * t + lm) * 72 + c * 32 + lg * 8;
            Bh[t][c] = *(const short8*)(sh + off);
            Bl[t][c] = *(const short8*)(sl + off);
        }
    }

    const float4* rp0;
    {
        int nr = blockIdx.x * 1024 + w * 16 + lm;
        int nrc = nr < NSCORE ? nr : NSCORE - 1;
        rp0 = (const float4*)(ax + (size_t)nrc * 64);
    }
    float4 q0 = rp0[lg * 2], q1 = rp0[lg * 2 + 1];
    float4 q2 = rp0[8 + lg * 2], q3 = rp0[9 + lg * 2];

    #pragma unroll 1
    for (int s = 0; s < 16; ++s) {
        float4 p0, p1, p2, p3;
        if (s < 15) {
            int nr = blockIdx.x * 1024 + (s + 1) * 64 + w * 16 + lm;
            int nrc = nr < NSCORE ? nr : NSCORE - 1;
            const float4* np = (const float4*)(ax + (size_t)nrc * 64);
            p0 = np[lg * 2];     p1 = np[lg * 2 + 1];
            p2 = np[8 + lg * 2]; p3 = np[9 + lg * 2];
        }

        short8 Ah[2], Al[2];
        split8(q0, q1, Ah[0], Al[0]);
        split8(q2, q3, Ah[1], Al[1]);

        f32x4 acc[4];
        #pragma unroll
        for (int t = 0; t < 4; ++t) acc[t] = (f32x4){0.f, 0.f, 0.f, 0.f};

        #pragma unroll
        for (int t = 0; t < 4; ++t) {
            #pragma unroll
            for (int c = 0; c < 2; ++c) {
                acc[t] = __builtin_amdgcn_mfma_f32_16x16x32_bf16(Ah[c], Bh[t][c], acc[t], 0, 0, 0);
                acc[t] = __builtin_amdgcn_mfma_f32_16x16x32_bf16(Ah[c], Bl[t][c], acc[t], 0, 0, 0);
                acc[t] = __builtin_amdgcn_mfma_f32_16x16x32_bf16(Al[c], Bh[t][c], acc[t], 0, 0, 0);
            }
        }

        const int n0 = blockIdx.x * 1024 + s * 64 + w * 16;
        #pragma unroll
        for (int t = 0; t < 4; ++t) {
            #pragma unroll
            for (int r = 0; r < 4; ++r) {
                float v = acc[t][r];
                int n = n0 + lg * 4 + r;
                if (v > THRF && n < NSCORE) {
                    int row = t * 16 + lm;
                    unsigned int p = atomicAdd(&scnt[row], 1u);
                    if (p < BCAP2) { sval[row][p] = v; sidx[row][p] = n; }
                }
            }
        }
        q0 = p0; q1 = p1; q2 = p2; q3 = p3;
    }
    __syncthreads();

    if (tid < 64) {
        unsigned int c = min(scnt[tid], (unsigned int)BCAP2);
        sbase[tid] = c ? atomicAdd(&cnt[tid], c) : 0u;
    }
    __syncthreads();

    for (int s = tid; s < 64 * BCAP2; s += 256) {
        int bb = s >> 6, j = s & (BCAP2 - 1);
        if (j < (int)min(scnt[bb], (unsigned int)BCAP2)) {
            unsigned int pos = sbase[bb] + (unsigned int)j;
            if (pos < ROWCAP) {
                candv[(size_t)bb * ROWCAP + pos] = sval[bb][j];
                candi[(size_t)bb * ROWCAP + pos] = sidx[bb][j];
            }
        }
    }
}

// ------- K3: hist cutoff -> exact f32 recompute -> exact top-16 -------
__global__ __launch_bounds__(256) void k_select(const unsigned int* __restrict__ cnt,
                                                const float* __restrict__ candv,
                                                const int* __restrict__ candi,
                                                const float* __restrict__ ax,
                                                const float* __restrict__ bxR,
                                                float* __restrict__ out,
                                                int* __restrict__ tkidx) {
    __shared__ unsigned int hist[NBIN];
    __shared__ float colv[COLCAP];
    __shared__ int   coli[COLCAP];
    __shared__ int   colc;
    __shared__ int   Bsh;
    const int b = blockIdx.x;
    const int t = threadIdx.x;

    for (int i = t; i < NBIN; i += 256) hist[i] = 0;
    if (t == 0) { colc = 0; Bsh = 0; }
    __syncthreads();

    const int cs = (int)min(cnt[b], (unsigned int)ROWCAP);
    for (int i = t; i < cs; i += 256) {
        float v = candv[(size_t)b * ROWCAP + i];
        int bin = (int)((v - HLO3) * HSC3);
        bin = bin < 0 ? 0 : (bin > NBIN - 1 ? NBIN - 1 : bin);
        atomicAdd(&hist[bin], 1u);
    }
    __syncthreads();

    if (t < 64) {
        const int base = 1023 - t * 16;
        unsigned int loc[16]; unsigned int sg = 0;
        #pragma unroll
        for (int j = 0; j < 16; ++j) { loc[j] = hist[base - j]; sg += loc[j]; }
        unsigned int cum = sg;
        #pragma unroll
        for (int off = 1; off < 64; off <<= 1) {
            unsigned int u = __shfl_up(cum, off);
            if (t >= off) cum += u;
        }
        unsigned int prev = cum - sg;
        if ((prev < 16u) && (cum >= 16u)) {
            unsigned int run = prev; int Bv = 0;
            #pragma unroll
            for (int j = 0; j < 16; ++j) {
                run += loc[j];
                if (run >= 16u) { Bv = base - j; break; }
            }
            Bsh = Bv;
        }
    }
    __syncthreads();
    const int B2 = Bsh >= 2 ? Bsh - 2 : 0;

    for (int i = t; i < cs; i += 256) {
        float v = candv[(size_t)b * ROWCAP + i];
        int bin = (int)((v - HLO3) * HSC3);
        bin = bin < 0 ? 0 : (bin > NBIN - 1 ? NBIN - 1 : bin);
        if (bin >= B2) {
            int p = atomicAdd(&colc, 1);
            if (p < COLCAP) { colv[p] = v; coli[p] = candi[(size_t)b * ROWCAP + i]; }
        }
    }
    __syncthreads();

    {
        int m = colc; if (m > COLCAP) m = COLCAP;
        if (t < m) {
            int idx = coli[t];
            idx = idx < 0 ? 0 : (idx > NSCORE - 1 ? NSCORE - 1 : idx);
            const float4* arw = (const float4*)(ax + (size_t)idx * 64);
            const float4* brw = (const float4*)(bxR + b * 64);
            float s = 0.f;
            #pragma unroll
            for (int i = 0; i < 16; ++i) {
                float4 av = arw[i], bv = brw[i];
                s = fmaf(av.x, bv.x, s);
                s = fmaf(av.y, bv.y, s);
                s = fmaf(av.z, bv.z, s);
                s = fmaf(av.w, bv.w, s);
            }
            colv[t] = s;
        }
    }
    __syncthreads();

    if (t < 64) {
        int m = colc; if (m > COLCAP) m = COLCAP;
        float v0 = (t      < m) ? colv[t]      : -INFINITY;
        float v1 = (t + 64 < m) ? colv[t + 64] : -INFINITY;
        int i0 = (t      < m) ? coli[t]      : 0x7FFFFFFF;
        int i1 = (t + 64 < m) ? coli[t + 64] : 0x7FFFFFFF;
        for (int r = 0; r < 16; ++r) {
            float bv; int bi; int bs;
            if (better(v0, i0, v1, i1)) { bv = v0; bi = i0; bs = 0; }
            else                        { bv = v1; bi = i1; bs = 1; }
            int bl = t;
            #pragma unroll
            for (int off = 32; off > 0; off >>= 1) {
                float ov = __shfl_xor(bv, off);
                int oi = __shfl_xor(bi, off);
                int ol = __shfl_xor(bl, off);
                int os = __shfl_xor(bs, off);
                if (better(ov, oi, bv, bi)) { bv = ov; bi = oi; bl = ol; bs = os; }
            }
            if (t == 0) { out[b * 16 + r] = bv; tkidx[b * 16 + r] = bi; }
            if (t == bl) {
                if (bs == 0) { v0 = -INFINITY; i0 = 0x7FFFFFFF; }
                else         { v1 = -INFINITY; i1 = 0x7FFFFFFF; }
            }
        }
    }
}

// ---------------- K4: gather windows + transpose (1024 parallel blocks) ----------------
__global__ __launch_bounds__(128) void k_gather(const float* __restrict__ win,
                                                const int* __restrict__ tkidx,
                                                float* __restrict__ out) {
    __shared__ float sm[9 * 128];
    const int bk = blockIdx.x;
    const int l = threadIdx.x;
    int idx = tkidx[bk];
    idx = idx < 0 ? 0 : (idx > NSCORE - 1 ? NSCORE - 1 : idx);
    const float* src = win + (size_t)idx * 1152;
    #pragma unroll
    for (int c = 0; c < 9; ++c) sm[c * 128 + l] = src[c * 128 + l];
    __syncthreads();
    float* dst = out + 1024 + (size_t)bk * 1152;
    #pragma unroll
    for (int q = 0; q < 9; ++q) {
        int j = q * 128 + l;
        dst[j] = sm[(j % 9) * 128 + (j / 9)];
    }
}

extern "C" void kernel_launch(void* const* d_in, const int* in_sizes, int n_in,
                              void* d_out, int out_size, void* d_ws, size_t ws_size,
                              hipStream_t stream) {
    const float* x   = (const float*)d_in[0];
    const float* ax  = (const float*)d_in[1];
    const float* win = (const float*)d_in[2];
    const float* w1  = (const float*)d_in[3];
    const float* b1  = (const float*)d_in[4];
    const float* w2  = (const float*)d_in[5];
    const float* b2  = (const float*)d_in[6];
    const float* w3  = (const float*)d_in[7];
    const float* b3  = (const float*)d_in[8];
    const float* w4  = (const float*)d_in[9];
    const float* b4  = (const float*)d_in[10];
    const float* wf  = (const float*)d_in[11];
    float* out = (float*)d_out;

    float* wsf = (float*)d_ws;
    float* bxR = wsf;                                   // 4096 f32
    u16*   bxh = (u16*)(wsf + 4096);                    // 4096 u16
    u16*   bxl = bxh + 4096;                            // 4096 u16
    unsigned int* cntp = (unsigned int*)(bxl + 4096);   // 64 u32
    float* candv = (float*)(cntp + 64);                 // 64*4096 f32
    int*   candi = (int*)(candv + (size_t)64 * ROWCAP); // 64*4096 i32
    int*   tkidx = candi + (size_t)64 * ROWCAP;         // 1024 i32

    hipLaunchKernelGGL(k_encoder, dim3(64), dim3(512), 0, stream,
                       x, w1, b1, w2, b2, w3, b3, w4, b4, wf, bxR, bxh, bxl, cntp);
    hipLaunchKernelGGL(k_scores, dim3(196), dim3(256), 0, stream,
                       ax, bxh, bxl, cntp, candv, candi);
    hipLaunchKernelGGL(k_select, dim3(64), dim3(256), 0, stream,
                       cntp, candv, candi, ax, bxR, out, tkidx);
    hipLaunchKernelGGL(k_gather, dim3(64 * 16), dim3(128), 0, stream,
                       win, tkidx, out);
}

// Round 12
// 58.878 us; speedup vs baseline: 149.1720x; 1.0683x over previous
//
#include <hip/hip_runtime.h>
#include <math.h>

#define NSCORE 200000
#define THRF   0.30f
#define ROWCAP 4096
#define BCAP2  64
#define NBIN   1024
#define HLO3   0.30f
#define HSC3   2275.5556f   // NBIN / 0.45
#define COLCAP 128

typedef unsigned short u16;
typedef __attribute__((ext_vector_type(8))) short short8;
typedef __attribute__((ext_vector_type(4))) float f32x4;
typedef __attribute__((ext_vector_type(4))) unsigned int uint4v;

__device__ __forceinline__ bool better(float av, int ai, float bv, int bi) {
    return (av > bv) || (av == bv && ai < bi);
}

__device__ __forceinline__ void split8(float4 a, float4 b, short8& hi, short8& lo) {
    float f[8] = {a.x, a.y, a.z, a.w, b.x, b.y, b.z, b.w};
    uint4v H, L;
    #pragma unroll
    for (int i = 0; i < 4; ++i) {
        unsigned ue = __float_as_uint(f[2 * i]);
        unsigned uo = __float_as_uint(f[2 * i + 1]);
        unsigned he = ue & 0xFFFF0000u;
        unsigned ho = uo & 0xFFFF0000u;
        float le  = f[2 * i]     - __uint_as_float(he);
        float lo_ = f[2 * i + 1] - __uint_as_float(ho);
        H[i] = (he >> 16) | ho;
        L[i] = (__float_as_uint(le) >> 16) | (__float_as_uint(lo_) & 0xFFFF0000u);
    }
    hi = __builtin_bit_cast(short8, H);
    lo = __builtin_bit_cast(short8, L);
}

// ---- K1a: conv+GELU+pool for one (batch, branch); weights in LDS; 256 blocks ----
__global__ __launch_bounds__(128) void k_enc1(
    const float* __restrict__ x,
    const float* __restrict__ w1, const float* __restrict__ b1,
    const float* __restrict__ w2, const float* __restrict__ b2,
    const float* __restrict__ w3, const float* __restrict__ b3,
    const float* __restrict__ w4, const float* __restrict__ b4,
    float* __restrict__ vecsum) {
    __shared__ float xs[8][128];      // SoA: lanes stride-1 -> conflict-free
    __shared__ float sw[400];         // weights (<=384) + 16 biases @384
    __shared__ float sacc[128 * 17];  // [l][i], stride 17 -> conflict-free
    __shared__ float part[8][16];
    const int blk = blockIdx.x;
    const int b = blk >> 2, g = blk & 3;
    const int l = threadIdx.x;

    {   // stage weights/bias into LDS (coalesced)
        const float* W  = (g == 0) ? w1 : (g == 1) ? w2 : (g == 2) ? w3 : w4;
        const float* Bb = (g == 0) ? b1 : (g == 1) ? b2 : (g == 2) ? b3 : b4;
        const int nw = (g == 0) ? 128 : 384;
        for (int i = l; i < nw; i += 128) sw[i] = W[i];
        if (l < 16) sw[384 + l] = Bb[l];
    }
    float xr[8];
    {   // stage x[b] (4 KB) + keep own row in registers
        const float4* xrow = (const float4*)(x + (size_t)b * 1024 + l * 8);
        float4 a = xrow[0], c4 = xrow[1];
        xr[0] = a.x; xr[1] = a.y; xr[2] = a.z; xr[3] = a.w;
        xr[4] = c4.x; xr[5] = c4.y; xr[6] = c4.z; xr[7] = c4.w;
        xs[0][l] = a.x;  xs[1][l] = a.y;  xs[2][l] = a.z;  xs[3][l] = a.w;
        xs[4][l] = c4.x; xs[5][l] = c4.y; xs[6][l] = c4.z; xs[7][l] = c4.w;
    }
    __syncthreads();

    const int dil = (g == 0) ? 0 : (1 << (g - 1));
    #pragma unroll 1
    for (int i = 0; i < 16; ++i) {
        float val = sw[384 + i];
        if (g == 0) {
            #pragma unroll
            for (int c = 0; c < 8; ++c) val = fmaf(sw[i * 8 + c], xr[c], val);
        } else {
            int ll = l - dil;                              // left tap
            if (ll >= 0) {
                #pragma unroll
                for (int c = 0; c < 8; ++c) val = fmaf(sw[i * 24 + c * 3 + 0], xs[c][ll], val);
            }
            #pragma unroll                                  // center tap (registers)
            for (int c = 0; c < 8; ++c) val = fmaf(sw[i * 24 + c * 3 + 1], xr[c], val);
            ll = l + dil;                                   // right tap
            if (ll < 128) {
                #pragma unroll
                for (int c = 0; c < 8; ++c) val = fmaf(sw[i * 24 + c * 3 + 2], xs[c][ll], val);
            }
        }
        val = 0.5f * val * (1.0f + erff(val * 0.70710678118654752f));  // exact GELU
        sacc[l * 17 + i] = val;
    }
    __syncthreads();
    {   // reduce over l, bitwise-identical tree to R11 (h*16+j partition, pairwise combine)
        int oo = l & 15, h = l >> 4;
        float vs = 0.f;
        #pragma unroll
        for (int j = 0; j < 16; ++j) vs += sacc[(h * 16 + j) * 17 + oo];
        part[h][oo] = vs;
    }
    __syncthreads();
    if (l < 16) {
        float v = ((part[0][l] + part[1][l]) + (part[2][l] + part[3][l]))
                + ((part[4][l] + part[5][l]) + (part[6][l] + part[7][l]));
        vecsum[b * 64 + g * 16 + l] = v * (1.0f / 128.0f);
    }
}

// ---- K1b: matmul + LN + L2norm + bf16 split; 64 blocks x 64 threads; zeroes cnt ----
__global__ __launch_bounds__(64) void k_enc2(const float* __restrict__ vecsum,
                                             const float* __restrict__ wf,
                                             float* __restrict__ bxR,
                                             u16* __restrict__ bxh, u16* __restrict__ bxl,
                                             unsigned int* __restrict__ cnt) {
    __shared__ float vecs[64];
    const int b = blockIdx.x, tid = threadIdx.x;
    if (tid == 0) cnt[b] = 0;
    vecs[tid] = vecsum[b * 64 + tid];
    __syncthreads();

    const float* wr = wf + tid * 64;
    float o = 0.f;
    #pragma unroll
    for (int j = 0; j < 64; ++j) o = fmaf(vecs[j], wr[j], o);
    float mu = o;
    #pragma unroll
    for (int off = 32; off > 0; off >>= 1) mu += __shfl_xor(mu, off);
    mu *= (1.0f / 64.0f);
    float d = o - mu;
    float s2 = d * d;
    #pragma unroll
    for (int off = 32; off > 0; off >>= 1) s2 += __shfl_xor(s2, off);
    float ln = d / sqrtf(s2 * (1.0f / 64.0f) + 1e-5f);
    float n2 = ln * ln;
    #pragma unroll
    for (int off = 32; off > 0; off >>= 1) n2 += __shfl_xor(n2, off);
    float nrm = sqrtf(n2);
    float v = ln / fmaxf(nrm, 1e-12f);
    bxR[b * 64 + tid] = v;
    unsigned u = __float_as_uint(v);
    unsigned h = u & 0xFFFF0000u;
    float lo = v - __uint_as_float(h);
    bxh[b * 64 + tid] = (u16)(u >> 16);
    bxl[b * 64 + tid] = (u16)(__float_as_uint(lo) >> 16);
}

// ------- K2: MFMA scores, 1024 rows/block (16 segs), depth-1 prefetch (unchanged R11) -------
__global__ __launch_bounds__(256) void k_scores(const float* __restrict__ ax,
                                                const u16* __restrict__ bxh,
                                                const u16* __restrict__ bxl,
                                                unsigned int* __restrict__ cnt,
                                                float* __restrict__ candv,
                                                int* __restrict__ candi) {
    __shared__ uint4v shv[576];
    __shared__ uint4v slv[576];
    __shared__ float sval[64][BCAP2];
    __shared__ int   sidx[64][BCAP2];
    __shared__ unsigned int scnt[64];
    __shared__ unsigned int sbase[64];
    const int tid = threadIdx.x;

    {
        const uint4v* srch = (const uint4v*)bxh;
        const uint4v* srcl = (const uint4v*)bxl;
        for (int i = tid; i < 512; i += 256) {
            int r = i >> 3, j = i & 7;
            shv[r * 9 + j] = srch[i];
            slv[r * 9 + j] = srcl[i];
        }
    }
    if (tid < 64) scnt[tid] = 0;
    __syncthreads();

    const int lane = tid & 63;
    const int w = tid >> 6;
    const int lm = lane & 15;
    const int lg = lane >> 4;

    short8 Bh[4][2], Bl[4][2];
    const u16* sh = (const u16*)shv;
    const u16* sl = (const u16*)slv;
    #pragma unroll
    for (int t = 0; t < 4; ++t) {
        #pragma unroll
        for (int c = 0; c < 2; ++c) {
            int off = (16 * t + lm) * 72 + c * 32 + lg * 8;
            Bh[t][c] = *(const short8*)(sh + off);
            Bl[t][c] = *(const short8*)(sl + off);
        }
    }

    const float4* rp0;
    {
        int nr = blockIdx.x * 1024 + w * 16 + lm;
        int nrc = nr < NSCORE ? nr : NSCORE - 1;
        rp0 = (const float4*)(ax + (size_t)nrc * 64);
    }
    float4 q0 = rp0[lg * 2], q1 = rp0[lg * 2 + 1];
    float4 q2 = rp0[8 + lg * 2], q3 = rp0[9 + lg * 2];

    #pragma unroll 1
    for (int s = 0; s < 16; ++s) {
        float4 p0, p1, p2, p3;
        if (s < 15) {
            int nr = blockIdx.x * 1024 + (s + 1) * 64 + w * 16 + lm;
            int nrc = nr < NSCORE ? nr : NSCORE - 1;
            const float4* np = (const float4*)(ax + (size_t)nrc * 64);
            p0 = np[lg * 2];     p1 = np[lg * 2 + 1];
            p2 = np[8 + lg * 2]; p3 = np[9 + lg * 2];
        }

        short8 Ah[2], Al[2];
        split8(q0, q1, Ah[0], Al[0]);
        split8(q2, q3, Ah[1], Al[1]);

        f32x4 acc[4];
        #pragma unroll
        for (int t = 0; t < 4; ++t) acc[t] = (f32x4){0.f, 0.f, 0.f, 0.f};

        #pragma unroll
        for (int t = 0; t < 4; ++t) {
            #pragma unroll
            for (int c = 0; c < 2; ++c) {
                acc[t] = __builtin_amdgcn_mfma_f32_16x16x32_bf16(Ah[c], Bh[t][c], acc[t], 0, 0, 0);
                acc[t] = __builtin_amdgcn_mfma_f32_16x16x32_bf16(Ah[c], Bl[t][c], acc[t], 0, 0, 0);
                acc[t] = __builtin_amdgcn_mfma_f32_16x16x32_bf16(Al[c], Bh[t][c], acc[t], 0, 0, 0);
            }
        }

        const int n0 = blockIdx.x * 1024 + s * 64 + w * 16;
        #pragma unroll
        for (int t = 0; t < 4; ++t) {
            #pragma unroll
            for (int r = 0; r < 4; ++r) {
                float v = acc[t][r];
                int n = n0 + lg * 4 + r;
                if (v > THRF && n < NSCORE) {
                    int row = t * 16 + lm;
                    unsigned int p = atomicAdd(&scnt[row], 1u);
                    if (p < BCAP2) { sval[row][p] = v; sidx[row][p] = n; }
                }
            }
        }
        q0 = p0; q1 = p1; q2 = p2; q3 = p3;
    }
    __syncthreads();

    if (tid < 64) {
        unsigned int c = min(scnt[tid], (unsigned int)BCAP2);
        sbase[tid] = c ? atomicAdd(&cnt[tid], c) : 0u;
    }
    __syncthreads();

    for (int s = tid; s < 64 * BCAP2; s += 256) {
        int bb = s >> 6, j = s & (BCAP2 - 1);
        if (j < (int)min(scnt[bb], (unsigned int)BCAP2)) {
            unsigned int pos = sbase[bb] + (unsigned int)j;
            if (pos < ROWCAP) {
                candv[(size_t)bb * ROWCAP + pos] = sval[bb][j];
                candi[(size_t)bb * ROWCAP + pos] = sidx[bb][j];
            }
        }
    }
}

// ------- K3: hist cutoff -> exact f32 recompute -> exact top-16 (unchanged R11) -------
__global__ __launch_bounds__(256) void k_select(const unsigned int* __restrict__ cnt,
                                                const float* __restrict__ candv,
                                                const int* __restrict__ candi,
                                                const float* __restrict__ ax,
                                                const float* __restrict__ bxR,
                                                float* __restrict__ out,
                                                int* __restrict__ tkidx) {
    __shared__ unsigned int hist[NBIN];
    __shared__ float colv[COLCAP];
    __shared__ int   coli[COLCAP];
    __shared__ int   colc;
    __shared__ int   Bsh;
    const int b = blockIdx.x;
    const int t = threadIdx.x;

    for (int i = t; i < NBIN; i += 256) hist[i] = 0;
    if (t == 0) { colc = 0; Bsh = 0; }
    __syncthreads();

    const int cs = (int)min(cnt[b], (unsigned int)ROWCAP);
    for (int i = t; i < cs; i += 256) {
        float v = candv[(size_t)b * ROWCAP + i];
        int bin = (int)((v - HLO3) * HSC3);
        bin = bin < 0 ? 0 : (bin > NBIN - 1 ? NBIN - 1 : bin);
        atomicAdd(&hist[bin], 1u);
    }
    __syncthreads();

    if (t < 64) {
        const int base = 1023 - t * 16;
        unsigned int loc[16]; unsigned int sg = 0;
        #pragma unroll
        for (int j = 0; j < 16; ++j) { loc[j] = hist[base - j]; sg += loc[j]; }
        unsigned int cum = sg;
        #pragma unroll
        for (int off = 1; off < 64; off <<= 1) {
            unsigned int u = __shfl_up(cum, off);
            if (t >= off) cum += u;
        }
        unsigned int prev = cum - sg;
        if ((prev < 16u) && (cum >= 16u)) {
            unsigned int run = prev; int Bv = 0;
            #pragma unroll
            for (int j = 0; j < 16; ++j) {
                run += loc[j];
                if (run >= 16u) { Bv = base - j; break; }
            }
            Bsh = Bv;
        }
    }
    __syncthreads();
    const int B2 = Bsh >= 2 ? Bsh - 2 : 0;

    for (int i = t; i < cs; i += 256) {
        float v = candv[(size_t)b * ROWCAP + i];
        int bin = (int)((v - HLO3) * HSC3);
        bin = bin < 0 ? 0 : (bin > NBIN - 1 ? NBIN - 1 : bin);
        if (bin >= B2) {
            int p = atomicAdd(&colc, 1);
            if (p < COLCAP) { colv[p] = v; coli[p] = candi[(size_t)b * ROWCAP + i]; }
        }
    }
    __syncthreads();

    {
        int m = colc; if (m > COLCAP) m = COLCAP;
        if (t < m) {
            int idx = coli[t];
            idx = idx < 0 ? 0 : (idx > NSCORE - 1 ? NSCORE - 1 : idx);
            const float4* arw = (const float4*)(ax + (size_t)idx * 64);
            const float4* brw = (const float4*)(bxR + b * 64);
            float s = 0.f;
            #pragma unroll
            for (int i = 0; i < 16; ++i) {
                float4 av = arw[i], bv = brw[i];
                s = fmaf(av.x, bv.x, s);
                s = fmaf(av.y, bv.y, s);
                s = fmaf(av.z, bv.z, s);
                s = fmaf(av.w, bv.w, s);
            }
            colv[t] = s;
        }
    }
    __syncthreads();

    if (t < 64) {
        int m = colc; if (m > COLCAP) m = COLCAP;
        float v0 = (t      < m) ? colv[t]      : -INFINITY;
        float v1 = (t + 64 < m) ? colv[t + 64] : -INFINITY;
        int i0 = (t      < m) ? coli[t]      : 0x7FFFFFFF;
        int i1 = (t + 64 < m) ? coli[t + 64] : 0x7FFFFFFF;
        for (int r = 0; r < 16; ++r) {
            float bv; int bi; int bs;
            if (better(v0, i0, v1, i1)) { bv = v0; bi = i0; bs = 0; }
            else                        { bv = v1; bi = i1; bs = 1; }
            int bl = t;
            #pragma unroll
            for (int off = 32; off > 0; off >>= 1) {
                float ov = __shfl_xor(bv, off);
                int oi = __shfl_xor(bi, off);
                int ol = __shfl_xor(bl, off);
                int os = __shfl_xor(bs, off);
                if (better(ov, oi, bv, bi)) { bv = ov; bi = oi; bl = ol; bs = os; }
            }
            if (t == 0) { out[b * 16 + r] = bv; tkidx[b * 16 + r] = bi; }
            if (t == bl) {
                if (bs == 0) { v0 = -INFINITY; i0 = 0x7FFFFFFF; }
                else         { v1 = -INFINITY; i1 = 0x7FFFFFFF; }
            }
        }
    }
}

// ---------------- K4: gather windows + transpose (unchanged R11) ----------------
__global__ __launch_bounds__(128) void k_gather(const float* __restrict__ win,
                                                const int* __restrict__ tkidx,
                                                float* __restrict__ out) {
    __shared__ float sm[9 * 128];
    const int bk = blockIdx.x;
    const int l = threadIdx.x;
    int idx = tkidx[bk];
    idx = idx < 0 ? 0 : (idx > NSCORE - 1 ? NSCORE - 1 : idx);
    const float* src = win + (size_t)idx * 1152;
    #pragma unroll
    for (int c = 0; c < 9; ++c) sm[c * 128 + l] = src[c * 128 + l];
    __syncthreads();
    float* dst = out + 1024 + (size_t)bk * 1152;
    #pragma unroll
    for (int q = 0; q < 9; ++q) {
        int j = q * 128 + l;
        dst[j] = sm[(j % 9) * 128 + (j / 9)];
    }
}

extern "C" void kernel_launch(void* const* d_in, const int* in_sizes, int n_in,
                              void* d_out, int out_size, void* d_ws, size_t ws_size,
                              hipStream_t stream) {
    const float* x   = (const float*)d_in[0];
    const float* ax  = (const float*)d_in[1];
    const float* win = (const float*)d_in[2];
    const float* w1  = (const float*)d_in[3];
    const float* b1  = (const float*)d_in[4];
    const float* w2  = (const float*)d_in[5];
    const float* b2  = (const float*)d_in[6];
    const float* w3  = (const float*)d_in[7];
    const float* b3  = (const float*)d_in[8];
    const float* w4  = (const float*)d_in[9];
    const float* b4  = (const float*)d_in[10];
    const float* wf  = (const float*)d_in[11];
    float* out = (float*)d_out;

    float* wsf = (float*)d_ws;
    float* bxR = wsf;                                   // 4096 f32
    u16*   bxh = (u16*)(wsf + 4096);                    // 4096 u16
    u16*   bxl = bxh + 4096;                            // 4096 u16
    unsigned int* cntp = (unsigned int*)(bxl + 4096);   // 64 u32
    float* candv = (float*)(cntp + 64);                 // 64*4096 f32
    int*   candi = (int*)(candv + (size_t)64 * ROWCAP); // 64*4096 i32
    int*   tkidx = candi + (size_t)64 * ROWCAP;         // 1024 i32
    float* vecsum = (float*)(tkidx + 1024);             // 4096 f32

    hipLaunchKernelGGL(k_enc1, dim3(256), dim3(128), 0, stream,
                       x, w1, b1, w2, b2, w3, b3, w4, b4, vecsum);
    hipLaunchKernelGGL(k_enc2, dim3(64), dim3(64), 0, stream,
                       vecsum, wf, bxR, bxh, bxl, cntp);
    hipLaunchKernelGGL(k_scores, dim3(196), dim3(256), 0, stream,
                       ax, bxh, bxl, cntp, candv, candi);
    hipLaunchKernelGGL(k_select, dim3(64), dim3(256), 0, stream,
                       cntp, candv, candi, ax, bxR, out, tkidx);
    hipLaunchKernelGGL(k_gather, dim3(64 * 16), dim3(128), 0, stream,
                       win, tkidx, out);
}